// Round 10
// baseline (1247.438 us; speedup 1.0000x reference)
//
#include <hip/hip_runtime.h>

#define BATCH 16
#define PS 784          // nodes per partition; LDS acc = 784*17*4 = 53312 B
#define STRIDE 17       // padded per-node LDS stride (floats)
#define NPART 64        // 64*784 = 50176 >= 50001
#define PAIRS (NPART * NPART)   // 4096 (owner, remote) bins
#define SLICES 8        // accumulate blocks per partition
#define NB (NPART * SLICES)    // 512 accumulate blocks
#define SB 128          // hist/scatter blocks
#define TPB 1024

typedef unsigned int uint4v __attribute__((ext_vector_type(4)));

// fast tanh: 1 - 2/(e^{2z}+1); rel err ~1e-6 vs 2.6e-4 threshold
static __device__ __forceinline__ float fast_tanh(float z) {
    float ez = __expf(2.0f * z);
    return 1.0f - 2.0f * __builtin_amdgcn_rcpf(ez + 1.0f);
}

// aux_T[(N+1)][16]: node-major transpose of x with a zero row at node 0.
__global__ void build_aux_T(const float* __restrict__ x, float* __restrict__ auxT, int n) {
    int idx = blockIdx.x * blockDim.x + threadIdx.x;
    if (idx >= BATCH * n) return;
    int b = idx / n;
    int i = idx % n;
    auxT[(i + 1) * BATCH + b] = x[idx];
    if (idx < BATCH) auxT[idx] = 0.0f;
}

// ---------------- pair-binned sorted-record path ----------------

__global__ __launch_bounds__(TPB)
void pair_hist(const int* __restrict__ src, const int* __restrict__ des,
               unsigned* __restrict__ hist, int E) {
    __shared__ unsigned h[PAIRS];
    int tid = threadIdx.x;
    for (int i = tid; i < PAIRS; i += TPB) h[i] = 0;
    __syncthreads();
    long t = (long)blockIdx.x * TPB + tid;
    long stride = (long)gridDim.x * TPB * 4;
    for (long e0 = t * 4; e0 < E; e0 += stride) {
        int ne = (int)min((long)4, (long)E - e0);
        if (ne == 4) {
            int4 sv = *(const int4*)(src + e0);
            int4 dv = *(const int4*)(des + e0);
            int ss[4] = {sv.x, sv.y, sv.z, sv.w};
            int dd[4] = {dv.x, dv.y, dv.z, dv.w};
#pragma unroll
            for (int j = 0; j < 4; ++j) {
                int ps = ss[j] / PS, pd = dd[j] / PS;
                atomicAdd(&h[ps * NPART + pd], 1u);
                if (pd != ps) atomicAdd(&h[pd * NPART + ps], 1u);
            }
        } else {
            for (int j = 0; j < ne; ++j) {
                int ps = src[e0 + j] / PS, pd = des[e0 + j] / PS;
                atomicAdd(&h[ps * NPART + pd], 1u);
                if (pd != ps) atomicAdd(&h[pd * NPART + ps], 1u);
            }
        }
    }
    __syncthreads();
    for (int i = tid; i < PAIRS; i += TPB)
        hist[(size_t)blockIdx.x * PAIRS + i] = h[i];
}

__global__ __launch_bounds__(TPB)
void totals_kernel(const unsigned* __restrict__ hist, unsigned* __restrict__ binTotal) {
    int tid = threadIdx.x;
    int bin = blockIdx.x * 64 + (tid >> 4);
    int j = tid & 15;
    unsigned s = 0;
    for (int r = j; r < SB; r += 16) s += hist[(size_t)r * PAIRS + bin];
#pragma unroll
    for (int m = 1; m < 16; m <<= 1) s += __shfl_xor(s, m, 64);
    if (j == 0) binTotal[bin] = s;
}

__global__ __launch_bounds__(1024)
void scan_totals(const unsigned* __restrict__ binTotal, unsigned* __restrict__ binStart,
                 unsigned* __restrict__ ownerStart, unsigned* __restrict__ ownerTotal) {
    __shared__ unsigned wsum[16];
    __shared__ unsigned oStart[NPART + 1];
    int tid = threadIdx.x;
    int lane = tid & 63;
    unsigned v[4];
    unsigned s = 0;
#pragma unroll
    for (int k = 0; k < 4; ++k) { v[k] = binTotal[tid * 4 + k]; s += v[k]; }
    unsigned inc = s;
    for (int off = 1; off < 64; off <<= 1) {
        unsigned t = __shfl_up(inc, off, 64);
        if (lane >= off) inc += t;
    }
    if (lane == 63) wsum[tid >> 6] = inc;
    __syncthreads();
    if (tid < 16) {
        unsigned w = wsum[tid];
        unsigned winc = w;
        for (int off = 1; off < 16; off <<= 1) {
            unsigned t = __shfl_up(winc, off, 64);
            if (tid >= off) winc += t;
        }
        wsum[tid] = winc - w;
    }
    __syncthreads();
    unsigned excl = (inc - s) + wsum[tid >> 6];
    unsigned run = excl;
#pragma unroll
    for (int k = 0; k < 4; ++k) { binStart[tid * 4 + k] = run; run += v[k]; }
    if ((tid & 15) == 0) oStart[tid >> 4] = excl;
    if (tid == 1023) oStart[NPART] = excl + s;
    __syncthreads();
    if (tid < NPART) {
        ownerStart[tid] = oStart[tid];
        ownerTotal[tid] = oStart[tid + 1] - oStart[tid];
    }
}

__global__ __launch_bounds__(TPB)
void offsets_kernel(unsigned* __restrict__ hist, const unsigned* __restrict__ binStart) {
    int tid = threadIdx.x;
    int binLocal = tid >> 4;
    int bin = blockIdx.x * 64 + binLocal;
    int j = tid & 15;
    const int per = SB / 16;
    unsigned cs = 0;
    for (int r = j * per; r < (j + 1) * per; ++r) cs += hist[(size_t)r * PAIRS + bin];
    int waveBase = (binLocal & 3) * 16;
    unsigned excl = 0;
    for (int k = 0; k < 16; ++k) {
        unsigned vv = __shfl(cs, waveBase + k, 64);
        if (k < j) excl += vv;
    }
    unsigned run = binStart[bin] + excl;
    for (int r = j * per; r < (j + 1) * per; ++r) {
        unsigned t = hist[(size_t)r * PAIRS + bin];
        hist[(size_t)r * PAIRS + bin] = run;
        run += t;
    }
}

__global__ __launch_bounds__(TPB)
void scatter_pair(const int* __restrict__ src, const int* __restrict__ des,
                  const float* __restrict__ param, const unsigned* __restrict__ offsets,
                  uint4* __restrict__ records, int E) {
    __shared__ unsigned offs[PAIRS];
    int tid = threadIdx.x;
    for (int i = tid; i < PAIRS; i += TPB)
        offs[i] = offsets[(size_t)blockIdx.x * PAIRS + i];
    __syncthreads();
    long t = (long)blockIdx.x * TPB + tid;
    long stride = (long)gridDim.x * TPB * 4;
    for (long e0 = t * 4; e0 < E; e0 += stride) {
        int ne = (int)min((long)4, (long)E - e0);
        int ss[4], dd[4];
        float aa[4], ww[4], cc[4];
        if (ne == 4) {
            int4 sv = *(const int4*)(src + e0);
            int4 dv = *(const int4*)(des + e0);
            float4 av = *(const float4*)(param + e0);
            float4 wv = *(const float4*)(param + E + e0);
            float4 cv = *(const float4*)(param + 2 * (size_t)E + e0);
            ss[0]=sv.x; ss[1]=sv.y; ss[2]=sv.z; ss[3]=sv.w;
            dd[0]=dv.x; dd[1]=dv.y; dd[2]=dv.z; dd[3]=dv.w;
            aa[0]=av.x; aa[1]=av.y; aa[2]=av.z; aa[3]=av.w;
            ww[0]=wv.x; ww[1]=wv.y; ww[2]=wv.z; ww[3]=wv.w;
            cc[0]=cv.x; cc[1]=cv.y; cc[2]=cv.z; cc[3]=cv.w;
        } else {
            for (int j = 0; j < ne; ++j) {
                ss[j] = src[e0 + j]; dd[j] = des[e0 + j];
                aa[j] = param[e0 + j]; ww[j] = param[E + e0 + j];
                cc[j] = param[2 * (size_t)E + e0 + j];
            }
        }
        for (int j = 0; j < ne; ++j) {
            int s = ss[j], d = dd[j];
            uint4 rec = make_uint4((unsigned)s | ((unsigned)d << 16),
                                   __float_as_uint(aa[j]), __float_as_uint(ww[j]),
                                   __float_as_uint(cc[j]));
            int ps = s / PS, pd = d / PS;
            unsigned slot = atomicAdd(&offs[ps * NPART + pd], 1u);
            records[slot] = rec;
            if (pd != ps) {
                unsigned slot2 = atomicAdd(&offs[pd * NPART + ps], 1u);
                records[slot2] = rec;
            }
        }
    }
}

// ---- accumulate ablation: V bit0=load records, bit1=load aux, bit2=LDS atomics ----
template<int V>
static __device__ __forceinline__
void accum_body(const uint4* __restrict__ records, const float* __restrict__ auxT,
                const unsigned* __restrict__ binStart, const unsigned* __restrict__ binTotal,
                float* __restrict__ partials) {
    __shared__ float acc[PS * STRIDE];
    int p = blockIdx.x >> 3;
    int sl = blockIdx.x & (SLICES - 1);
    int tid = threadIdx.x;
    for (int i = tid; i < PS * STRIDE; i += TPB) acc[i] = 0.0f;
    __syncthreads();
    unsigned bs = binStart[p], cnt = binTotal[p];
    unsigned lo = bs + (unsigned)(((unsigned long long)cnt * sl) / SLICES);
    unsigned hi = bs + (unsigned)(((unsigned long long)cnt * (sl + 1)) / SLICES);
    int base = p * PS;
    int g = tid >> 2;
    int lj = tid & 3;
    const unsigned G = TPB / 4;
    const uint4v* recv = (const uint4v*)records;
    const float4* aux4 = (const float4*)auxT;
    int bb = lj * 4;

    for (unsigned r = lo + g; r < hi; r += G) {
        uint4v rec;
        if (V & 1) {
            rec = __builtin_nontemporal_load(&recv[r]);
        } else {
            unsigned u = r * 2654435761u;
            unsigned sS = (unsigned)base + __umulhi(u, (unsigned)PS);
            unsigned sD = __umulhi(u ^ 0x9E3779B9u, 50001u);
            rec.x = sS | (sD << 16);
            rec.y = (u & 0x007FFFFFu) | 0x3C000000u;
            rec.z = ((u >> 3) & 0x007FFFFFu) | 0x3C000000u;
            rec.w = ((u >> 5) & 0x007FFFFFu) | 0x3C000000u;
        }
        int s = (int)(rec.x & 0xFFFFu);
        int d = (int)(rec.x >> 16);
        float4 vs, vd;
        if (V & 2) {
            vs = aux4[s * 4 + lj];
            vd = aux4[d * 4 + lj];
        } else {
            float fy = __uint_as_float(rec.y);
            float fz = __uint_as_float(rec.z);
            vs = make_float4(fy, fy, fy, fy);
            vd = make_float4(fz, fz, fz, fz);
        }
        float a = __uint_as_float(rec.y);
        float w = __uint_as_float(rec.z);
        float c = __uint_as_float(rec.w);
        float st0 = a * fast_tanh(w * (vs.x - vd.x) + c);
        float st1 = a * fast_tanh(w * (vs.y - vd.y) + c);
        float st2 = a * fast_tanh(w * (vs.z - vd.z) + c);
        float st3 = a * fast_tanh(w * (vs.w - vd.w) + c);
        if (V & 4) {
            unsigned ls = (unsigned)(s - base), ld = (unsigned)(d - base);
            if (ls < PS) {
                float* as_ = &acc[ls * STRIDE + bb];
                atomicAdd(as_ + 0, -st0);
                atomicAdd(as_ + 1, -st1);
                atomicAdd(as_ + 2, -st2);
                atomicAdd(as_ + 3, -st3);
            }
            if (ld < PS) {
                float* ad_ = &acc[ld * STRIDE + bb];
                atomicAdd(ad_ + 0, st0);
                atomicAdd(ad_ + 1, st1);
                atomicAdd(ad_ + 2, st2);
                atomicAdd(ad_ + 3, st3);
            }
        } else {
            asm volatile("" :: "v"(st0), "v"(st1), "v"(st2), "v"(st3));
        }
    }
    __syncthreads();
    float* myPart = partials + (size_t)blockIdx.x * (PS * BATCH);
    for (int i = tid; i < PS * BATCH; i += TPB)
        myPart[i] = acc[(i >> 4) * STRIDE + (i & 15)];
}

__global__ __launch_bounds__(TPB, 8)
void abl_A_recaux(const uint4* __restrict__ r, const float* __restrict__ a,
                  const unsigned* __restrict__ bs, const unsigned* __restrict__ bt,
                  float* __restrict__ p) { accum_body<3>(r, a, bs, bt, p); }

__global__ __launch_bounds__(TPB, 8)
void abl_B_recatom(const uint4* __restrict__ r, const float* __restrict__ a,
                   const unsigned* __restrict__ bs, const unsigned* __restrict__ bt,
                   float* __restrict__ p) { accum_body<5>(r, a, bs, bt, p); }

__global__ __launch_bounds__(TPB, 8)
void abl_C_auxatom(const uint4* __restrict__ r, const float* __restrict__ a,
                   const unsigned* __restrict__ bs, const unsigned* __restrict__ bt,
                   float* __restrict__ p) { accum_body<6>(r, a, bs, bt, p); }

__global__ __launch_bounds__(TPB, 8)
void abl_D_atomonly(const uint4* __restrict__ r, const float* __restrict__ a,
                    const unsigned* __restrict__ bs, const unsigned* __restrict__ bt,
                    float* __restrict__ p) { accum_body<4>(r, a, bs, bt, p); }

__global__ __launch_bounds__(TPB, 8)
void accumulate_full(const uint4* __restrict__ r, const float* __restrict__ a,
                     const unsigned* __restrict__ bs, const unsigned* __restrict__ bt,
                     float* __restrict__ p) { accum_body<7>(r, a, bs, bt, p); }

__global__ void reduce_sorted(const float* __restrict__ partials,
                              float* __restrict__ out, int n) {
    int idx = blockIdx.x * blockDim.x + threadIdx.x;
    if (idx >= BATCH * n) return;
    int b = idx / n;
    int j = idx % n;
    int i = j + 1;
    int p = i / PS;
    int local = i - p * PS;
    const float* basep = partials + (size_t)p * SLICES * (PS * BATCH)
                         + (size_t)local * BATCH + b;
    float sum = 0.0f;
#pragma unroll
    for (int sl = 0; sl < SLICES; ++sl) sum += basep[(size_t)sl * (PS * BATCH)];
    out[idx] = sum;
}

// ---------------- fallback: direct device atomics ----------------
__global__ void edge_direct(const float* __restrict__ param,
                            const int* __restrict__ src,
                            const int* __restrict__ des,
                            const float* __restrict__ x,
                            float* __restrict__ out, int E, int n) {
    int e = blockIdx.x * blockDim.x + threadIdx.x;
    if (e >= E) return;
    float a = param[e], w = param[E + e], c = param[2 * E + e];
    int s = src[e], d = des[e];
#pragma unroll
    for (int b = 0; b < BATCH; ++b) {
        float vs = s ? x[(size_t)b * n + (s - 1)] : 0.0f;
        float vd = d ? x[(size_t)b * n + (d - 1)] : 0.0f;
        float st = a * tanhf(w * (vs - vd) + c);
        if (s) atomicAdd(out + (size_t)b * n + (s - 1), -st);
        if (d) atomicAdd(out + (size_t)b * n + (d - 1), st);
    }
}

extern "C" void kernel_launch(void* const* d_in, const int* in_sizes, int n_in,
                              void* d_out, int out_size, void* d_ws, size_t ws_size,
                              hipStream_t stream) {
    const float* x     = (const float*)d_in[1];
    const float* param = (const float*)d_in[2];
    const int*   src   = (const int*)d_in[3];
    const int*   des   = (const int*)d_in[4];
    float* out = (float*)d_out;

    int E = in_sizes[3];
    int n = in_sizes[1] / BATCH;   // N = 50000
    int total = BATCH * n;

    auto alignup = [](size_t v) { return (v + 255) & ~(size_t)255; };
    size_t auxBytes   = alignup((size_t)(n + 1) * BATCH * sizeof(float));
    size_t recBytes   = alignup((size_t)2 * E * sizeof(uint4));
    size_t pairBytes  = alignup((size_t)SB * PAIRS * sizeof(unsigned));
    size_t bsBytes    = alignup((size_t)PAIRS * sizeof(unsigned));
    size_t ownBytes   = alignup((size_t)NPART * sizeof(unsigned));
    size_t partBytes  = alignup((size_t)NB * PS * BATCH * sizeof(float));
    size_t needPair   = auxBytes + recBytes + pairBytes + 2 * bsBytes + 2 * ownBytes + partBytes;

    if (ws_size >= needPair && (n + 1) <= NPART * PS && n <= 65535) {
        char* w = (char*)d_ws;
        float*    auxT      = (float*)w;     w += auxBytes;
        uint4*    records   = (uint4*)w;     w += recBytes;
        unsigned* pairHist  = (unsigned*)w;  w += pairBytes;
        unsigned* binStart  = (unsigned*)w;  w += bsBytes;
        unsigned* binTotal  = (unsigned*)w;  w += bsBytes;
        unsigned* ownerStart= (unsigned*)w;  w += ownBytes;
        unsigned* ownerTotal= (unsigned*)w;  w += ownBytes;
        float*    partials  = (float*)w;

        build_aux_T<<<(total + 255) / 256, 256, 0, stream>>>(x, auxT, n);
        pair_hist<<<SB, TPB, 0, stream>>>(src, des, pairHist, E);
        totals_kernel<<<PAIRS / 64, TPB, 0, stream>>>(pairHist, binTotal);
        scan_totals<<<1, 1024, 0, stream>>>(binTotal, binStart, ownerStart, ownerTotal);
        offsets_kernel<<<PAIRS / 64, TPB, 0, stream>>>(pairHist, binStart);
        scatter_pair<<<SB, TPB, 0, stream>>>(src, des, param, pairHist, records, E);

        // ---- ablation dispatches (diagnostic; full overwrites partials after) ----
        abl_A_recaux  <<<NB, TPB, 0, stream>>>(records, auxT, ownerStart, ownerTotal, partials);
        abl_B_recatom <<<NB, TPB, 0, stream>>>(records, auxT, ownerStart, ownerTotal, partials);
        abl_C_auxatom <<<NB, TPB, 0, stream>>>(records, auxT, ownerStart, ownerTotal, partials);
        abl_D_atomonly<<<NB, TPB, 0, stream>>>(records, auxT, ownerStart, ownerTotal, partials);

        accumulate_full<<<NB, TPB, 0, stream>>>(records, auxT, ownerStart, ownerTotal, partials);
        reduce_sorted<<<(total + 255) / 256, 256, 0, stream>>>(partials, out, n);
        return;
    }

    (void)hipMemsetAsync(out, 0, (size_t)out_size * sizeof(float), stream);
    edge_direct<<<(E + 255) / 256, 256, 0, stream>>>(param, src, des, x, out, E, n);
}

// Round 11
// 146.444 us; speedup vs baseline: 8.5182x; 8.5182x over previous
//
#include <hip/hip_runtime.h>

#define BATCH 16
#define PS 196               // nodes per partition
#define NPART 256            // 256*196 = 50176 >= 50001
#define NT (NPART * PS)
#define SB 256               // hist/scatter blocks
#define TPB 1024

// fast tanh: 1 - 2/(e^{2z}+1); rel err ~1e-6 vs 2.6e-4 threshold
static __device__ __forceinline__ float fast_tanh(float z) {
    float ez = __expf(2.0f * z);
    return 1.0f - 2.0f * __builtin_amdgcn_rcpf(ez + 1.0f);
}

// aux_T[(N+1)][16]: node-major transpose of x with a zero row at node 0.
__global__ void build_aux_T(const float* __restrict__ x, float* __restrict__ auxT, int n) {
    int idx = blockIdx.x * blockDim.x + threadIdx.x;
    if (idx >= BATCH * n) return;
    int b = idx / n;
    int i = idx % n;
    auxT[(i + 1) * BATCH + b] = x[idx];
    if (idx < BATCH) auxT[idx] = 0.0f;
}

// Histogram of OWNER-endpoint partitions (2 records per edge), partitions [p0,p1).
__global__ __launch_bounds__(TPB)
void hist1(const int* __restrict__ src, const int* __restrict__ des,
           unsigned* __restrict__ blockHist, int E, int p0, int p1) {
    __shared__ unsigned h[NPART];
    int np = p1 - p0;
    int tid = threadIdx.x;
    for (int i = tid; i < np; i += TPB) h[i] = 0;
    __syncthreads();
    long t = (long)blockIdx.x * TPB + tid;
    long stride = (long)gridDim.x * TPB * 4;
    for (long e0 = t * 4; e0 < E; e0 += stride) {
        int ne = (int)min((long)4, (long)E - e0);
        int ss[4], dd[4];
        if (ne == 4) {
            int4 sv = *(const int4*)(src + e0);
            int4 dv = *(const int4*)(des + e0);
            ss[0]=sv.x; ss[1]=sv.y; ss[2]=sv.z; ss[3]=sv.w;
            dd[0]=dv.x; dd[1]=dv.y; dd[2]=dv.z; dd[3]=dv.w;
        } else {
            for (int j = 0; j < ne; ++j) { ss[j] = src[e0+j]; dd[j] = des[e0+j]; }
        }
        for (int j = 0; j < ne; ++j) {
            int ps = ss[j] / PS, pd = dd[j] / PS;
            if (ps >= p0 && ps < p1) atomicAdd(&h[ps - p0], 1u);
            if (pd >= p0 && pd < p1) atomicAdd(&h[pd - p0], 1u);
        }
    }
    __syncthreads();
    for (int i = tid; i < np; i += TPB)
        blockHist[(size_t)blockIdx.x * np + i] = h[i];
}

// Single block: per-partition totals + exclusive scan + in-place per-block offsets.
__global__ __launch_bounds__(TPB)
void scan1(unsigned* __restrict__ blockHist, unsigned* __restrict__ partStart, int np) {
    __shared__ unsigned tot[NPART];
    __shared__ unsigned bst[NPART + 1];
    int tid = threadIdx.x;
    int b = tid >> 2, q = tid & 3;       // 256 bins x 4 quarter-threads
    const int ROWS = SB / 4;             // 64 rows per quarter
    unsigned partial = 0;
    if (b < np)
        for (int r = q * ROWS; r < (q + 1) * ROWS; ++r)
            partial += blockHist[(size_t)r * np + b];
    unsigned t0 = partial;
    t0 += __shfl_xor(t0, 1, 64);
    t0 += __shfl_xor(t0, 2, 64);
    if (b < np && q == 0) tot[b] = t0;
    __syncthreads();
    if (tid == 0) {
        unsigned run = 0;
        for (int i = 0; i < np; ++i) { bst[i] = run; run += tot[i]; }
        bst[np] = run;
    }
    __syncthreads();
    if (tid <= np) partStart[tid] = bst[tid];
    if (b < np) {
        int lbase = (b & 15) * 4;
        unsigned qpre = 0;
        for (int qq = 0; qq < 4; ++qq) {
            unsigned v = __shfl(partial, lbase + qq, 64);
            if (qq < q) qpre += v;
        }
        unsigned run = bst[b] + qpre;
        for (int r = q * ROWS; r < (q + 1) * ROWS; ++r) {
            unsigned tmp = blockHist[(size_t)r * np + b];
            blockHist[(size_t)r * np + b] = run;
            run += tmp;
        }
    }
}

// Emit 2 owner-endpoint records per edge, signs folded into (a,w):
//   owner=s: {s|d<<16, -a, +w, c};  owner=d: {d|s<<16, +a, -w, c}
// contribution (uniform): acc[owner] += a' * tanh(w' * (v_owner - v_remote) + c)
__global__ __launch_bounds__(TPB)
void scatter1(const int* __restrict__ src, const int* __restrict__ des,
              const float* __restrict__ param, const unsigned* __restrict__ offsets,
              uint4* __restrict__ bins, int E, int p0, int p1) {
    __shared__ unsigned offs[NPART];
    int np = p1 - p0;
    int tid = threadIdx.x;
    for (int i = tid; i < np; i += TPB)
        offs[i] = offsets[(size_t)blockIdx.x * np + i];
    __syncthreads();
    long t = (long)blockIdx.x * TPB + tid;
    long stride = (long)gridDim.x * TPB * 4;
    for (long e0 = t * 4; e0 < E; e0 += stride) {
        int ne = (int)min((long)4, (long)E - e0);
        int ss[4], dd[4];
        float aa[4], ww[4], cc[4];
        if (ne == 4) {
            int4 sv = *(const int4*)(src + e0);
            int4 dv = *(const int4*)(des + e0);
            float4 av = *(const float4*)(param + e0);
            float4 wv = *(const float4*)(param + E + e0);
            float4 cv = *(const float4*)(param + 2 * (size_t)E + e0);
            ss[0]=sv.x; ss[1]=sv.y; ss[2]=sv.z; ss[3]=sv.w;
            dd[0]=dv.x; dd[1]=dv.y; dd[2]=dv.z; dd[3]=dv.w;
            aa[0]=av.x; aa[1]=av.y; aa[2]=av.z; aa[3]=av.w;
            ww[0]=wv.x; ww[1]=wv.y; ww[2]=wv.z; ww[3]=wv.w;
            cc[0]=cv.x; cc[1]=cv.y; cc[2]=cv.z; cc[3]=cv.w;
        } else {
            for (int j = 0; j < ne; ++j) {
                ss[j] = src[e0+j]; dd[j] = des[e0+j];
                aa[j] = param[e0+j]; ww[j] = param[E + e0 + j];
                cc[j] = param[2 * (size_t)E + e0 + j];
            }
        }
        for (int j = 0; j < ne; ++j) {
            int s = ss[j], d = dd[j];
            int ps = s / PS, pd = d / PS;
            if (ps >= p0 && ps < p1) {
                unsigned slot = atomicAdd(&offs[ps - p0], 1u);
                bins[slot] = make_uint4((unsigned)s | ((unsigned)d << 16),
                                        __float_as_uint(-aa[j]), __float_as_uint(ww[j]),
                                        __float_as_uint(cc[j]));
            }
            if (pd >= p0 && pd < p1) {
                unsigned slot = atomicAdd(&offs[pd - p0], 1u);
                bins[slot] = make_uint4((unsigned)d | ((unsigned)s << 16),
                                        __float_as_uint(aa[j]), __float_as_uint(-ww[j]),
                                        __float_as_uint(cc[j]));
            }
        }
    }
}

// One block per partition: counting-sort its records by owner node.
// Also emits nodeStart[] (global record ranges per node).
__global__ __launch_bounds__(TPB)
void sort2(const uint4* __restrict__ bins, uint4* __restrict__ sorted,
           const unsigned* __restrict__ partStart, unsigned* __restrict__ nodeStart,
           int p0) {
    __shared__ unsigned h[PS];
    int b = blockIdx.x;
    int p = p0 + b;
    int tid = threadIdx.x;
    unsigned lo = partStart[b], hi = partStart[b + 1];
    for (int i = tid; i < PS; i += TPB) h[i] = 0;
    __syncthreads();
    for (unsigned k = lo + tid; k < hi; k += TPB) {
        unsigned o = bins[k].x & 0xFFFFu;
        atomicAdd(&h[o - (unsigned)(p * PS)], 1u);
    }
    __syncthreads();
    if (tid == 0) {
        unsigned run = lo;
        int base = p * PS;
        for (int i = 0; i < PS; ++i) {
            unsigned s = h[i];
            nodeStart[base + i] = run;
            h[i] = run;          // absolute running counter for phase C
            run += s;
        }
        nodeStart[base + PS] = run;   // boundary (== next block's start; benign dup)
    }
    __syncthreads();
    for (unsigned k = lo + tid; k < hi; k += TPB) {
        uint4 rec = bins[k];
        unsigned local = (rec.x & 0xFFFFu) - (unsigned)(p * PS);
        unsigned slot = atomicAdd(&h[local], 1u);
        sorted[slot] = rec;
    }
}

// One WAVE per node: 16 records in flight (ri=lane>>2), lane owns 4 batches (lj).
// Register accumulation, shfl reduce, single float4 store. ZERO LDS / atomics.
__global__ __launch_bounds__(TPB)
void accumulate_nodes(const uint4* __restrict__ sorted, const float* __restrict__ auxT,
                      const unsigned* __restrict__ nodeStart, float* __restrict__ outT,
                      int nLo, int nHi) {
    int tid = threadIdx.x;
    int lane = tid & 63;
    int wave = blockIdx.x * (TPB / 64) + (tid >> 6);
    int nWaves = gridDim.x * (TPB / 64);
    int ri = lane >> 2, lj = lane & 3;
    const float4* aux4 = (const float4*)auxT;
    float4* out4 = (float4*)outT;

    for (int node = nLo + wave; node < nHi; node += nWaves) {
        unsigned lo = nodeStart[node], hi = nodeStart[node + 1];
        float4 vo = aux4[(size_t)node * 4 + lj];
        float ax = 0.0f, ay = 0.0f, az = 0.0f, aw = 0.0f;
        for (unsigned kk = lo; kk < hi; kk += 16) {
            unsigned k = kk + (unsigned)ri;
            uint4 rec;
            if (k < hi) rec = sorted[k];
            else { rec.x = 0u; rec.y = 0u; rec.z = 0u; rec.w = 0u; }
            unsigned rem = rec.x >> 16;
            float4 vr = aux4[(size_t)rem * 4 + lj];   // rem=0 -> zero row
            float a = __uint_as_float(rec.y);
            float w = __uint_as_float(rec.z);
            float c = __uint_as_float(rec.w);
            ax += a * fast_tanh(w * (vo.x - vr.x) + c);
            ay += a * fast_tanh(w * (vo.y - vr.y) + c);
            az += a * fast_tanh(w * (vo.z - vr.z) + c);
            aw += a * fast_tanh(w * (vo.w - vr.w) + c);
        }
#pragma unroll
        for (int m = 4; m < 64; m <<= 1) {
            ax += __shfl_xor(ax, m, 64);
            ay += __shfl_xor(ay, m, 64);
            az += __shfl_xor(az, m, 64);
            aw += __shfl_xor(aw, m, 64);
        }
        if (lane < 4)
            out4[(size_t)node * 4 + lane] = make_float4(ax, ay, az, aw);
    }
}

// out[b][j] = outT[j+1][b]  (drops node 0)
__global__ void transpose_out(const float* __restrict__ outT, float* __restrict__ out, int n) {
    int idx = blockIdx.x * blockDim.x + threadIdx.x;
    if (idx >= BATCH * n) return;
    int b = idx / n;
    int j = idx % n;
    out[idx] = outT[(size_t)(j + 1) * BATCH + b];
}

// ---------------- fallback: direct device atomics ----------------
__global__ void edge_direct(const float* __restrict__ param,
                            const int* __restrict__ src,
                            const int* __restrict__ des,
                            const float* __restrict__ x,
                            float* __restrict__ out, int E, int n) {
    int e = blockIdx.x * blockDim.x + threadIdx.x;
    if (e >= E) return;
    float a = param[e], w = param[E + e], c = param[2 * E + e];
    int s = src[e], d = des[e];
#pragma unroll
    for (int b = 0; b < BATCH; ++b) {
        float vs = s ? x[(size_t)b * n + (s - 1)] : 0.0f;
        float vd = d ? x[(size_t)b * n + (d - 1)] : 0.0f;
        float st = a * tanhf(w * (vs - vd) + c);
        if (s) atomicAdd(out + (size_t)b * n + (s - 1), -st);
        if (d) atomicAdd(out + (size_t)b * n + (d - 1), st);
    }
}

extern "C" void kernel_launch(void* const* d_in, const int* in_sizes, int n_in,
                              void* d_out, int out_size, void* d_ws, size_t ws_size,
                              hipStream_t stream) {
    const float* x     = (const float*)d_in[1];
    const float* param = (const float*)d_in[2];
    const int*   src   = (const int*)d_in[3];
    const int*   des   = (const int*)d_in[4];
    float* out = (float*)d_out;

    int E = in_sizes[3];
    int n = in_sizes[1] / BATCH;   // N = 50000
    int total = BATCH * n;

    auto alignup = [](size_t v) { return (v + 255) & ~(size_t)255; };
    size_t auxBytes  = alignup((size_t)(n + 1) * BATCH * sizeof(float));
    size_t outTBytes = auxBytes;
    size_t bhBytes   = alignup((size_t)SB * NPART * sizeof(unsigned));
    size_t psBytes   = alignup((size_t)(NPART + 1) * sizeof(unsigned));
    size_t nsBytes   = alignup((size_t)(NT + 1) * sizeof(unsigned));

    int npass = 0;
    size_t recCap = 0;
    const int cands[5] = {1, 2, 4, 8, 16};
    for (int ci = 0; ci < 5; ++ci) {
        int cand = cands[ci];
        size_t cap = (cand == 1) ? (size_t)2 * E
                                 : (size_t)(2.0 * E / cand * 1.08) + 4096;
        size_t need = auxBytes + outTBytes + bhBytes + psBytes + nsBytes
                      + 2 * alignup(cap * sizeof(uint4));
        if (ws_size >= need) { npass = cand; recCap = cap; break; }
    }

    if (npass > 0 && (n + 1) <= NT && n <= 65534) {
        char* w = (char*)d_ws;
        float*    auxT      = (float*)w;     w += auxBytes;
        float*    outT      = (float*)w;     w += outTBytes;
        unsigned* blockHist = (unsigned*)w;  w += bhBytes;
        unsigned* partStart = (unsigned*)w;  w += psBytes;
        unsigned* nodeStart = (unsigned*)w;  w += nsBytes;
        uint4*    bins      = (uint4*)w;     w += alignup(recCap * sizeof(uint4));
        uint4*    sorted    = (uint4*)w;

        build_aux_T<<<(total + 255) / 256, 256, 0, stream>>>(x, auxT, n);

        int ppp = NPART / npass;   // partitions per pass (256 divisible by 1..16)
        for (int pass = 0; pass < npass; ++pass) {
            int p0 = pass * ppp, p1 = p0 + ppp;
            hist1<<<SB, TPB, 0, stream>>>(src, des, blockHist, E, p0, p1);
            scan1<<<1, TPB, 0, stream>>>(blockHist, partStart, ppp);
            scatter1<<<SB, TPB, 0, stream>>>(src, des, param, blockHist, bins, E, p0, p1);
            sort2<<<ppp, TPB, 0, stream>>>(bins, sorted, partStart, nodeStart, p0);
            int nLo = p0 * PS; if (nLo < 1) nLo = 1;
            int nHi = p1 * PS; if (nHi > n + 1) nHi = n + 1;
            if (nLo < nHi)
                accumulate_nodes<<<1024, TPB, 0, stream>>>(sorted, auxT, nodeStart,
                                                           outT, nLo, nHi);
        }
        transpose_out<<<(total + 255) / 256, 256, 0, stream>>>(outT, out, n);
        return;
    }

    (void)hipMemsetAsync(out, 0, (size_t)out_size * sizeof(float), stream);
    edge_direct<<<(E + 255) / 256, 256, 0, stream>>>(param, src, des, x, out, E, n);
}

// Round 13
// 133.982 us; speedup vs baseline: 9.3105x; 1.0930x over previous
//
#include <hip/hip_runtime.h>

#define BATCH 16
#define PS 49                // nodes per partition
#define NPART 1024           // 1024*49 = 50176 >= 50001
#define SB 256               // hist/scatter blocks
#define TPB 1024
#define LDSCAP 3840          // records staged in LDS (mean 3136, +12.6 sigma); 61440 B

// fast tanh: 1 - 2/(e^{2z}+1); rel err ~1e-6 vs 2.6e-4 threshold
static __device__ __forceinline__ float fast_tanh(float z) {
    float ez = __expf(2.0f * z);
    return 1.0f - 2.0f * __builtin_amdgcn_rcpf(ez + 1.0f);
}

// aux_T[(N+1)][16]: node-major transpose of x with a zero row at node 0.
__global__ void build_aux_T(const float* __restrict__ x, float* __restrict__ auxT, int n) {
    int idx = blockIdx.x * blockDim.x + threadIdx.x;
    if (idx >= BATCH * n) return;
    int b = idx / n;
    int i = idx % n;
    auxT[(i + 1) * BATCH + b] = x[idx];
    if (idx < BATCH) auxT[idx] = 0.0f;
}

// Histogram of OWNER-endpoint partitions (2 records per edge).
__global__ __launch_bounds__(TPB)
void hist1(const int* __restrict__ src, const int* __restrict__ des,
           unsigned* __restrict__ blockHist, int E) {
    __shared__ unsigned h[NPART];
    int tid = threadIdx.x;
    for (int i = tid; i < NPART; i += TPB) h[i] = 0;
    __syncthreads();
    long t = (long)blockIdx.x * TPB + tid;
    long stride = (long)gridDim.x * TPB * 4;
    for (long e0 = t * 4; e0 < E; e0 += stride) {
        int ne = (int)min((long)4, (long)E - e0);
        int ss[4], dd[4];
        if (ne == 4) {
            int4 sv = *(const int4*)(src + e0);
            int4 dv = *(const int4*)(des + e0);
            ss[0]=sv.x; ss[1]=sv.y; ss[2]=sv.z; ss[3]=sv.w;
            dd[0]=dv.x; dd[1]=dv.y; dd[2]=dv.z; dd[3]=dv.w;
        } else {
            for (int j = 0; j < ne; ++j) { ss[j] = src[e0+j]; dd[j] = des[e0+j]; }
        }
        for (int j = 0; j < ne; ++j) {
            atomicAdd(&h[ss[j] / PS], 1u);
            atomicAdd(&h[dd[j] / PS], 1u);
        }
    }
    __syncthreads();
    for (int i = tid; i < NPART; i += TPB)
        blockHist[(size_t)blockIdx.x * NPART + i] = h[i];
}

// Single block, one thread per bin: totals + exclusive scan + in-place offsets.
__global__ __launch_bounds__(TPB)
void scan1(unsigned* __restrict__ blockHist, unsigned* __restrict__ partStart) {
    __shared__ unsigned bst[NPART + 1];
    int tid = threadIdx.x;              // == bin
    unsigned sum = 0;
    for (int r = 0; r < SB; ++r) sum += blockHist[(size_t)r * NPART + tid];
    bst[tid] = sum;
    __syncthreads();
    if (tid == 0) {
        unsigned run = 0;
        for (int i = 0; i < NPART; ++i) { unsigned t = bst[i]; bst[i] = run; run += t; }
        bst[NPART] = run;
    }
    __syncthreads();
    partStart[tid] = bst[tid];
    if (tid == 0) partStart[NPART] = bst[NPART];
    unsigned run = bst[tid];
    for (int r = 0; r < SB; ++r) {
        unsigned tmp = blockHist[(size_t)r * NPART + tid];
        blockHist[(size_t)r * NPART + tid] = run;
        run += tmp;
    }
}

// Emit 2 owner-endpoint records per edge, signs folded into (a,w):
//   owner=s: {s|d<<16, -a, +w, c};  owner=d: {d|s<<16, +a, -w, c}
__global__ __launch_bounds__(TPB)
void scatter1(const int* __restrict__ src, const int* __restrict__ des,
              const float* __restrict__ param, const unsigned* __restrict__ offsets,
              uint4* __restrict__ bins, int E) {
    __shared__ unsigned offs[NPART];
    int tid = threadIdx.x;
    for (int i = tid; i < NPART; i += TPB)
        offs[i] = offsets[(size_t)blockIdx.x * NPART + i];
    __syncthreads();
    long t = (long)blockIdx.x * TPB + tid;
    long stride = (long)gridDim.x * TPB * 4;
    for (long e0 = t * 4; e0 < E; e0 += stride) {
        int ne = (int)min((long)4, (long)E - e0);
        int ss[4], dd[4];
        float aa[4], ww[4], cc[4];
        if (ne == 4) {
            int4 sv = *(const int4*)(src + e0);
            int4 dv = *(const int4*)(des + e0);
            float4 av = *(const float4*)(param + e0);
            float4 wv = *(const float4*)(param + E + e0);
            float4 cv = *(const float4*)(param + 2 * (size_t)E + e0);
            ss[0]=sv.x; ss[1]=sv.y; ss[2]=sv.z; ss[3]=sv.w;
            dd[0]=dv.x; dd[1]=dv.y; dd[2]=dv.z; dd[3]=dv.w;
            aa[0]=av.x; aa[1]=av.y; aa[2]=av.z; aa[3]=av.w;
            ww[0]=wv.x; ww[1]=wv.y; ww[2]=wv.z; ww[3]=wv.w;
            cc[0]=cv.x; cc[1]=cv.y; cc[2]=cv.z; cc[3]=cv.w;
        } else {
            for (int j = 0; j < ne; ++j) {
                ss[j] = src[e0+j]; dd[j] = des[e0+j];
                aa[j] = param[e0+j]; ww[j] = param[E + e0 + j];
                cc[j] = param[2 * (size_t)E + e0 + j];
            }
        }
        for (int j = 0; j < ne; ++j) {
            int s = ss[j], d = dd[j];
            unsigned slot = atomicAdd(&offs[s / PS], 1u);
            bins[slot] = make_uint4((unsigned)s | ((unsigned)d << 16),
                                    __float_as_uint(-aa[j]), __float_as_uint(ww[j]),
                                    __float_as_uint(cc[j]));
            unsigned slot2 = atomicAdd(&offs[d / PS], 1u);
            bins[slot2] = make_uint4((unsigned)d | ((unsigned)s << 16),
                                     __float_as_uint(aa[j]), __float_as_uint(-ww[j]),
                                     __float_as_uint(cc[j]));
        }
    }
}

// Fused: one block per partition. Counting-sort the partition's bin into LDS,
// then one wave per node accumulates from LDS (registers + shfl, no atomics out).
// LDS: 3840*16 + tables = ~61.9 KB <= 64 KB limit -> 2 blocks/CU.
__global__ __launch_bounds__(TPB)
void sort_accumulate(const uint4* __restrict__ bins, const unsigned* __restrict__ partStart,
                     const float* __restrict__ auxT, float* __restrict__ outT, int n) {
    extern __shared__ uint4 srec[];                 // [LDSCAP]
    unsigned* bump = (unsigned*)(srec + LDSCAP);    // [PS]
    unsigned* ns   = bump + PS;                     // [PS+1]
    int p = blockIdx.x;
    int tid = threadIdx.x;
    unsigned lo = partStart[p], hi = partStart[p + 1];
    unsigned cnt = hi - lo;
    unsigned cl = cnt < (unsigned)LDSCAP ? cnt : (unsigned)LDSCAP;
    int base = p * PS;

    for (int i = tid; i < PS; i += TPB) bump[i] = 0;
    __syncthreads();
    // pass 1: histogram by owner node (keys only)
    const unsigned* keys = (const unsigned*)bins;
    for (unsigned k = tid; k < cl; k += TPB) {
        unsigned o = keys[(size_t)(lo + k) * 4] & 0xFFFFu;
        atomicAdd(&bump[o - (unsigned)base], 1u);
    }
    __syncthreads();
    if (tid == 0) {
        unsigned run = 0;
        for (int i = 0; i < PS; ++i) {
            unsigned c = bump[i];
            ns[i] = run;
            bump[i] = run;
            run += c;
        }
        ns[PS] = run;
    }
    __syncthreads();
    // pass 2: scatter global bin -> LDS sorted (bin is L2-hot from pass 1)
    for (unsigned k = tid; k < cl; k += TPB) {
        uint4 rec = bins[lo + k];
        unsigned slot = atomicAdd(&bump[(rec.x & 0xFFFFu) - (unsigned)base], 1u);
        srec[slot] = rec;
    }
    __syncthreads();
    // pass 3: wave per node, 16 records in flight, lane-quad owns 4 batches
    int lane = tid & 63;
    int wv = tid >> 6;                 // 0..15
    int ri = lane >> 2, lj = lane & 3;
    const float4* aux4 = (const float4*)auxT;
    float4* out4 = (float4*)outT;
    for (int nl = wv; nl < PS; nl += TPB / 64) {
        int node = base + nl;
        if (node == 0 || node > n) continue;
        unsigned l2 = ns[nl], h2 = ns[nl + 1];
        float4 vo = aux4[(size_t)node * 4 + lj];
        float ax = 0.0f, ay = 0.0f, az = 0.0f, as_ = 0.0f;
        for (unsigned kk = l2; kk < h2; kk += 16) {
            unsigned k = kk + (unsigned)ri;
            uint4 rec;
            if (k < h2) rec = srec[k];
            else { rec.x = 0u; rec.y = 0u; rec.z = 0u; rec.w = 0u; }
            unsigned rem = rec.x >> 16;
            float4 vr = aux4[(size_t)rem * 4 + lj];
            float a = __uint_as_float(rec.y);
            float w = __uint_as_float(rec.z);
            float c = __uint_as_float(rec.w);
            ax  += a * fast_tanh(w * (vo.x - vr.x) + c);
            ay  += a * fast_tanh(w * (vo.y - vr.y) + c);
            az  += a * fast_tanh(w * (vo.z - vr.z) + c);
            as_ += a * fast_tanh(w * (vo.w - vr.w) + c);
        }
        // overflow tail (normally empty): filtered scan of un-staged records
        for (unsigned kk = lo + cl; kk < hi; kk += 16) {
            unsigned k = kk + (unsigned)ri;
            uint4 rec;
            if (k < hi) rec = bins[k];
            else { rec.x = 0u; rec.y = 0u; rec.z = 0u; rec.w = 0u; }
            if ((int)(rec.x & 0xFFFFu) != node) rec.y = 0u;   // a=0 -> no contribution
            unsigned rem = rec.x >> 16;
            float4 vr = aux4[(size_t)rem * 4 + lj];
            float a = __uint_as_float(rec.y);
            float w = __uint_as_float(rec.z);
            float c = __uint_as_float(rec.w);
            ax  += a * fast_tanh(w * (vo.x - vr.x) + c);
            ay  += a * fast_tanh(w * (vo.y - vr.y) + c);
            az  += a * fast_tanh(w * (vo.z - vr.z) + c);
            as_ += a * fast_tanh(w * (vo.w - vr.w) + c);
        }
#pragma unroll
        for (int m = 4; m < 64; m <<= 1) {
            ax  += __shfl_xor(ax, m, 64);
            ay  += __shfl_xor(ay, m, 64);
            az  += __shfl_xor(az, m, 64);
            as_ += __shfl_xor(as_, m, 64);
        }
        if (lane < 4)
            out4[(size_t)node * 4 + lane] = make_float4(ax, ay, az, as_);
    }
}

// out[b][j] = outT[j+1][b]  (drops node 0)
__global__ void transpose_out(const float* __restrict__ outT, float* __restrict__ out, int n) {
    int idx = blockIdx.x * blockDim.x + threadIdx.x;
    if (idx >= BATCH * n) return;
    int b = idx / n;
    int j = idx % n;
    out[idx] = outT[(size_t)(j + 1) * BATCH + b];
}

// ---------------- fallback: direct device atomics ----------------
__global__ void edge_direct(const float* __restrict__ param,
                            const int* __restrict__ src,
                            const int* __restrict__ des,
                            const float* __restrict__ x,
                            float* __restrict__ out, int E, int n) {
    int e = blockIdx.x * blockDim.x + threadIdx.x;
    if (e >= E) return;
    float a = param[e], w = param[E + e], c = param[2 * E + e];
    int s = src[e], d = des[e];
#pragma unroll
    for (int b = 0; b < BATCH; ++b) {
        float vs = s ? x[(size_t)b * n + (s - 1)] : 0.0f;
        float vd = d ? x[(size_t)b * n + (d - 1)] : 0.0f;
        float st = a * tanhf(w * (vs - vd) + c);
        if (s) atomicAdd(out + (size_t)b * n + (s - 1), -st);
        if (d) atomicAdd(out + (size_t)b * n + (d - 1), st);
    }
}

extern "C" void kernel_launch(void* const* d_in, const int* in_sizes, int n_in,
                              void* d_out, int out_size, void* d_ws, size_t ws_size,
                              hipStream_t stream) {
    const float* x     = (const float*)d_in[1];
    const float* param = (const float*)d_in[2];
    const int*   src   = (const int*)d_in[3];
    const int*   des   = (const int*)d_in[4];
    float* out = (float*)d_out;

    int E = in_sizes[3];
    int n = in_sizes[1] / BATCH;   // N = 50000
    int total = BATCH * n;

    auto alignup = [](size_t v) { return (v + 255) & ~(size_t)255; };
    size_t auxBytes  = alignup((size_t)(n + 1) * BATCH * sizeof(float));
    size_t outTBytes = auxBytes;
    size_t bhBytes   = alignup((size_t)SB * NPART * sizeof(unsigned));
    size_t psBytes   = alignup((size_t)(NPART + 1) * sizeof(unsigned));
    size_t binBytes  = alignup((size_t)2 * E * sizeof(uint4));
    size_t need      = auxBytes + outTBytes + bhBytes + psBytes + binBytes;

    size_t saLds = (size_t)LDSCAP * sizeof(uint4) + (2 * PS + 1 + 8) * sizeof(unsigned);

    if (ws_size >= need && (n + 1) <= NPART * PS && n <= 65534) {
        char* w = (char*)d_ws;
        float*    auxT      = (float*)w;     w += auxBytes;
        float*    outT      = (float*)w;     w += outTBytes;
        unsigned* blockHist = (unsigned*)w;  w += bhBytes;
        unsigned* partStart = (unsigned*)w;  w += psBytes;
        uint4*    bins      = (uint4*)w;

        build_aux_T<<<(total + 255) / 256, 256, 0, stream>>>(x, auxT, n);
        hist1<<<SB, TPB, 0, stream>>>(src, des, blockHist, E);
        scan1<<<1, TPB, 0, stream>>>(blockHist, partStart);
        scatter1<<<SB, TPB, 0, stream>>>(src, des, param, blockHist, bins, E);
        sort_accumulate<<<NPART, TPB, saLds, stream>>>(bins, partStart, auxT, outT, n);
        transpose_out<<<(total + 255) / 256, 256, 0, stream>>>(outT, out, n);
        return;
    }

    (void)hipMemsetAsync(out, 0, (size_t)out_size * sizeof(float), stream);
    edge_direct<<<(E + 255) / 256, 256, 0, stream>>>(param, src, des, x, out, E, n);
}

// Round 14
// 127.118 us; speedup vs baseline: 9.8132x; 1.0540x over previous
//
#include <hip/hip_runtime.h>

#define BATCH 16
#define PS 49                // nodes per partition
#define NPART 1024           // 1024*49 = 50176 >= 50001
#define SB 256               // hist/scatter blocks
#define TPB 1024
#define LDSCAP 3840          // records staged in LDS (mean 3136, +12.6 sigma); 61440 B

// fast tanh: 1 - 2/(e^{2z}+1); rel err ~1e-6 vs 2.6e-4 threshold
static __device__ __forceinline__ float fast_tanh(float z) {
    float ez = __expf(2.0f * z);
    return 1.0f - 2.0f * __builtin_amdgcn_rcpf(ez + 1.0f);
}

// aux_T[(N+1)][16]: node-major transpose of x with a zero row at node 0.
__global__ void build_aux_T(const float* __restrict__ x, float* __restrict__ auxT, int n) {
    int idx = blockIdx.x * blockDim.x + threadIdx.x;
    if (idx >= BATCH * n) return;
    int b = idx / n;
    int i = idx % n;
    auxT[(i + 1) * BATCH + b] = x[idx];
    if (idx < BATCH) auxT[idx] = 0.0f;
}

// Histogram of OWNER-endpoint partitions (2 records per edge).
__global__ __launch_bounds__(TPB)
void hist1(const int* __restrict__ src, const int* __restrict__ des,
           unsigned* __restrict__ blockHist, int E) {
    __shared__ unsigned h[NPART];
    int tid = threadIdx.x;
    for (int i = tid; i < NPART; i += TPB) h[i] = 0;
    __syncthreads();
    long t = (long)blockIdx.x * TPB + tid;
    long stride = (long)gridDim.x * TPB * 4;
    for (long e0 = t * 4; e0 < E; e0 += stride) {
        int ne = (int)min((long)4, (long)E - e0);
        int ss[4], dd[4];
        if (ne == 4) {
            int4 sv = *(const int4*)(src + e0);
            int4 dv = *(const int4*)(des + e0);
            ss[0]=sv.x; ss[1]=sv.y; ss[2]=sv.z; ss[3]=sv.w;
            dd[0]=dv.x; dd[1]=dv.y; dd[2]=dv.z; dd[3]=dv.w;
        } else {
            for (int j = 0; j < ne; ++j) { ss[j] = src[e0+j]; dd[j] = des[e0+j]; }
        }
        for (int j = 0; j < ne; ++j) {
            atomicAdd(&h[ss[j] / PS], 1u);
            atomicAdd(&h[dd[j] / PS], 1u);
        }
    }
    __syncthreads();
    for (int i = tid; i < NPART; i += TPB)
        blockHist[(size_t)blockIdx.x * NPART + i] = h[i];
}

// Grid-parallel per-bin totals: 64 bins/block x 16 threads. Grid = NPART/64 = 16.
__global__ __launch_bounds__(TPB)
void totals_k(const unsigned* __restrict__ blockHist, unsigned* __restrict__ binTotal) {
    int tid = threadIdx.x;
    int bin = blockIdx.x * 64 + (tid >> 4);
    int j = tid & 15;
    unsigned s = 0;
    for (int r = j; r < SB; r += 16) s += blockHist[(size_t)r * NPART + bin];
#pragma unroll
    for (int m = 1; m < 16; m <<= 1) s += __shfl_xor(s, m, 64);
    if (j == 0) binTotal[bin] = s;
}

// One block: exclusive scan of 1024 bin totals -> partStart[0..1024].
__global__ __launch_bounds__(TPB)
void scan_bins(const unsigned* __restrict__ binTotal, unsigned* __restrict__ partStart) {
    __shared__ unsigned wsum[16];
    int tid = threadIdx.x;
    int lane = tid & 63, wv = tid >> 6;
    unsigned v = binTotal[tid];
    unsigned inc = v;
    for (int off = 1; off < 64; off <<= 1) {
        unsigned t = __shfl_up(inc, off, 64);
        if (lane >= off) inc += t;
    }
    if (lane == 63) wsum[wv] = inc;
    __syncthreads();
    if (tid < 16) {
        unsigned w = wsum[tid], winc = w;
        for (int off = 1; off < 16; off <<= 1) {
            unsigned t = __shfl_up(winc, off, 64);
            if (tid >= off) winc += t;
        }
        wsum[tid] = winc - w;
    }
    __syncthreads();
    unsigned excl = (inc - v) + wsum[wv];
    partStart[tid] = excl;
    if (tid == TPB - 1) partStart[NPART] = excl + v;
}

// Grid-parallel: blockHist -> per-(block,bin) scatter offsets. 64 bins/block x 16.
__global__ __launch_bounds__(TPB)
void offs_k(unsigned* __restrict__ blockHist, const unsigned* __restrict__ partStart) {
    int tid = threadIdx.x;
    int binLocal = tid >> 4;
    int bin = blockIdx.x * 64 + binLocal;
    int j = tid & 15;
    const int per = SB / 16;   // 16 contiguous rows per thread
    unsigned ls = 0;
    for (int r = j * per; r < (j + 1) * per; ++r)
        ls += blockHist[(size_t)r * NPART + bin];
    int waveBase = (binLocal & 3) * 16;
    unsigned excl = 0;
    for (int k = 0; k < 16; ++k) {
        unsigned v = __shfl(ls, waveBase + k, 64);
        if (k < j) excl += v;
    }
    unsigned run = partStart[bin] + excl;
    for (int r = j * per; r < (j + 1) * per; ++r) {
        unsigned tmp = blockHist[(size_t)r * NPART + bin];
        blockHist[(size_t)r * NPART + bin] = run;
        run += tmp;
    }
}

// Emit 2 owner-endpoint records per edge, signs folded into (a,w):
//   owner=s: {s|d<<16, -a, +w, c};  owner=d: {d|s<<16, +a, -w, c}
__global__ __launch_bounds__(TPB)
void scatter1(const int* __restrict__ src, const int* __restrict__ des,
              const float* __restrict__ param, const unsigned* __restrict__ offsets,
              uint4* __restrict__ bins, int E) {
    __shared__ unsigned offs[NPART];
    int tid = threadIdx.x;
    for (int i = tid; i < NPART; i += TPB)
        offs[i] = offsets[(size_t)blockIdx.x * NPART + i];
    __syncthreads();
    long t = (long)blockIdx.x * TPB + tid;
    long stride = (long)gridDim.x * TPB * 4;
    for (long e0 = t * 4; e0 < E; e0 += stride) {
        int ne = (int)min((long)4, (long)E - e0);
        int ss[4], dd[4];
        float aa[4], ww[4], cc[4];
        if (ne == 4) {
            int4 sv = *(const int4*)(src + e0);
            int4 dv = *(const int4*)(des + e0);
            float4 av = *(const float4*)(param + e0);
            float4 wv = *(const float4*)(param + E + e0);
            float4 cv = *(const float4*)(param + 2 * (size_t)E + e0);
            ss[0]=sv.x; ss[1]=sv.y; ss[2]=sv.z; ss[3]=sv.w;
            dd[0]=dv.x; dd[1]=dv.y; dd[2]=dv.z; dd[3]=dv.w;
            aa[0]=av.x; aa[1]=av.y; aa[2]=av.z; aa[3]=av.w;
            ww[0]=wv.x; ww[1]=wv.y; ww[2]=wv.z; ww[3]=wv.w;
            cc[0]=cv.x; cc[1]=cv.y; cc[2]=cv.z; cc[3]=cv.w;
        } else {
            for (int j = 0; j < ne; ++j) {
                ss[j] = src[e0+j]; dd[j] = des[e0+j];
                aa[j] = param[e0+j]; ww[j] = param[E + e0 + j];
                cc[j] = param[2 * (size_t)E + e0 + j];
            }
        }
        for (int j = 0; j < ne; ++j) {
            int s = ss[j], d = dd[j];
            unsigned slot = atomicAdd(&offs[s / PS], 1u);
            bins[slot] = make_uint4((unsigned)s | ((unsigned)d << 16),
                                    __float_as_uint(-aa[j]), __float_as_uint(ww[j]),
                                    __float_as_uint(cc[j]));
            unsigned slot2 = atomicAdd(&offs[d / PS], 1u);
            bins[slot2] = make_uint4((unsigned)d | ((unsigned)s << 16),
                                     __float_as_uint(aa[j]), __float_as_uint(-ww[j]),
                                     __float_as_uint(cc[j]));
        }
    }
}

// Fused: one block per partition. Counting-sort the partition's bin into LDS,
// then one wave per node accumulates from LDS (registers + shfl, no atomics out).
// LDS: 3840*16 + tables = ~61.9 KB <= 64 KB limit -> 2 blocks/CU.
__global__ __launch_bounds__(TPB)
void sort_accumulate(const uint4* __restrict__ bins, const unsigned* __restrict__ partStart,
                     const float* __restrict__ auxT, float* __restrict__ outT, int n) {
    extern __shared__ uint4 srec[];                 // [LDSCAP]
    unsigned* bump = (unsigned*)(srec + LDSCAP);    // [PS]
    unsigned* ns   = bump + PS;                     // [PS+1]
    int p = blockIdx.x;
    int tid = threadIdx.x;
    unsigned lo = partStart[p], hi = partStart[p + 1];
    unsigned cnt = hi - lo;
    unsigned cl = cnt < (unsigned)LDSCAP ? cnt : (unsigned)LDSCAP;
    int base = p * PS;

    for (int i = tid; i < PS; i += TPB) bump[i] = 0;
    __syncthreads();
    // pass 1: histogram by owner node (keys only)
    const unsigned* keys = (const unsigned*)bins;
    for (unsigned k = tid; k < cl; k += TPB) {
        unsigned o = keys[(size_t)(lo + k) * 4] & 0xFFFFu;
        atomicAdd(&bump[o - (unsigned)base], 1u);
    }
    __syncthreads();
    if (tid == 0) {
        unsigned run = 0;
        for (int i = 0; i < PS; ++i) {
            unsigned c = bump[i];
            ns[i] = run;
            bump[i] = run;
            run += c;
        }
        ns[PS] = run;
    }
    __syncthreads();
    // pass 2: scatter global bin -> LDS sorted (bin is L2-hot from pass 1)
    for (unsigned k = tid; k < cl; k += TPB) {
        uint4 rec = bins[lo + k];
        unsigned slot = atomicAdd(&bump[(rec.x & 0xFFFFu) - (unsigned)base], 1u);
        srec[slot] = rec;
    }
    __syncthreads();
    // pass 3: wave per node, 16 records in flight, lane-quad owns 4 batches
    int lane = tid & 63;
    int wv = tid >> 6;                 // 0..15
    int ri = lane >> 2, lj = lane & 3;
    const float4* aux4 = (const float4*)auxT;
    float4* out4 = (float4*)outT;
    for (int nl = wv; nl < PS; nl += TPB / 64) {
        int node = base + nl;
        if (node == 0 || node > n) continue;
        unsigned l2 = ns[nl], h2 = ns[nl + 1];
        float4 vo = aux4[(size_t)node * 4 + lj];
        float ax = 0.0f, ay = 0.0f, az = 0.0f, as_ = 0.0f;
        for (unsigned kk = l2; kk < h2; kk += 16) {
            unsigned k = kk + (unsigned)ri;
            uint4 rec;
            if (k < h2) rec = srec[k];
            else { rec.x = 0u; rec.y = 0u; rec.z = 0u; rec.w = 0u; }
            unsigned rem = rec.x >> 16;
            float4 vr = aux4[(size_t)rem * 4 + lj];
            float a = __uint_as_float(rec.y);
            float w = __uint_as_float(rec.z);
            float c = __uint_as_float(rec.w);
            ax  += a * fast_tanh(w * (vo.x - vr.x) + c);
            ay  += a * fast_tanh(w * (vo.y - vr.y) + c);
            az  += a * fast_tanh(w * (vo.z - vr.z) + c);
            as_ += a * fast_tanh(w * (vo.w - vr.w) + c);
        }
        // overflow tail (normally empty): filtered scan of un-staged records
        for (unsigned kk = lo + cl; kk < hi; kk += 16) {
            unsigned k = kk + (unsigned)ri;
            uint4 rec;
            if (k < hi) rec = bins[k];
            else { rec.x = 0u; rec.y = 0u; rec.z = 0u; rec.w = 0u; }
            if ((int)(rec.x & 0xFFFFu) != node) rec.y = 0u;   // a=0 -> no contribution
            unsigned rem = rec.x >> 16;
            float4 vr = aux4[(size_t)rem * 4 + lj];
            float a = __uint_as_float(rec.y);
            float w = __uint_as_float(rec.z);
            float c = __uint_as_float(rec.w);
            ax  += a * fast_tanh(w * (vo.x - vr.x) + c);
            ay  += a * fast_tanh(w * (vo.y - vr.y) + c);
            az  += a * fast_tanh(w * (vo.z - vr.z) + c);
            as_ += a * fast_tanh(w * (vo.w - vr.w) + c);
        }
#pragma unroll
        for (int m = 4; m < 64; m <<= 1) {
            ax  += __shfl_xor(ax, m, 64);
            ay  += __shfl_xor(ay, m, 64);
            az  += __shfl_xor(az, m, 64);
            as_ += __shfl_xor(as_, m, 64);
        }
        if (lane < 4)
            out4[(size_t)node * 4 + lane] = make_float4(ax, ay, az, as_);
    }
}

// out[b][j] = outT[j+1][b]  (drops node 0)
__global__ void transpose_out(const float* __restrict__ outT, float* __restrict__ out, int n) {
    int idx = blockIdx.x * blockDim.x + threadIdx.x;
    if (idx >= BATCH * n) return;
    int b = idx / n;
    int j = idx % n;
    out[idx] = outT[(size_t)(j + 1) * BATCH + b];
}

// ---------------- fallback: direct device atomics ----------------
__global__ void edge_direct(const float* __restrict__ param,
                            const int* __restrict__ src,
                            const int* __restrict__ des,
                            const float* __restrict__ x,
                            float* __restrict__ out, int E, int n) {
    int e = blockIdx.x * blockDim.x + threadIdx.x;
    if (e >= E) return;
    float a = param[e], w = param[E + e], c = param[2 * E + e];
    int s = src[e], d = des[e];
#pragma unroll
    for (int b = 0; b < BATCH; ++b) {
        float vs = s ? x[(size_t)b * n + (s - 1)] : 0.0f;
        float vd = d ? x[(size_t)b * n + (d - 1)] : 0.0f;
        float st = a * tanhf(w * (vs - vd) + c);
        if (s) atomicAdd(out + (size_t)b * n + (s - 1), -st);
        if (d) atomicAdd(out + (size_t)b * n + (d - 1), st);
    }
}

extern "C" void kernel_launch(void* const* d_in, const int* in_sizes, int n_in,
                              void* d_out, int out_size, void* d_ws, size_t ws_size,
                              hipStream_t stream) {
    const float* x     = (const float*)d_in[1];
    const float* param = (const float*)d_in[2];
    const int*   src   = (const int*)d_in[3];
    const int*   des   = (const int*)d_in[4];
    float* out = (float*)d_out;

    int E = in_sizes[3];
    int n = in_sizes[1] / BATCH;   // N = 50000
    int total = BATCH * n;

    auto alignup = [](size_t v) { return (v + 255) & ~(size_t)255; };
    size_t auxBytes  = alignup((size_t)(n + 1) * BATCH * sizeof(float));
    size_t outTBytes = auxBytes;
    size_t bhBytes   = alignup((size_t)SB * NPART * sizeof(unsigned));
    size_t psBytes   = alignup((size_t)(NPART + 1) * sizeof(unsigned));
    size_t btBytes   = alignup((size_t)NPART * sizeof(unsigned));
    size_t binBytes  = alignup((size_t)2 * E * sizeof(uint4));
    size_t need      = auxBytes + outTBytes + bhBytes + psBytes + btBytes + binBytes;

    size_t saLds = (size_t)LDSCAP * sizeof(uint4) + (2 * PS + 1 + 8) * sizeof(unsigned);

    if (ws_size >= need && (n + 1) <= NPART * PS && n <= 65534) {
        char* w = (char*)d_ws;
        float*    auxT      = (float*)w;     w += auxBytes;
        float*    outT      = (float*)w;     w += outTBytes;
        unsigned* blockHist = (unsigned*)w;  w += bhBytes;
        unsigned* partStart = (unsigned*)w;  w += psBytes;
        unsigned* binTotal  = (unsigned*)w;  w += btBytes;
        uint4*    bins      = (uint4*)w;

        build_aux_T<<<(total + 255) / 256, 256, 0, stream>>>(x, auxT, n);
        hist1<<<SB, TPB, 0, stream>>>(src, des, blockHist, E);
        totals_k<<<NPART / 64, TPB, 0, stream>>>(blockHist, binTotal);
        scan_bins<<<1, TPB, 0, stream>>>(binTotal, partStart);
        offs_k<<<NPART / 64, TPB, 0, stream>>>(blockHist, partStart);
        scatter1<<<SB, TPB, 0, stream>>>(src, des, param, blockHist, bins, E);
        sort_accumulate<<<NPART, TPB, saLds, stream>>>(bins, partStart, auxT, outT, n);
        transpose_out<<<(total + 255) / 256, 256, 0, stream>>>(outT, out, n);
        return;
    }

    (void)hipMemsetAsync(out, 0, (size_t)out_size * sizeof(float), stream);
    edge_direct<<<(E + 255) / 256, 256, 0, stream>>>(param, src, des, x, out, E, n);
}